// Round 5
// baseline (169.120 us; speedup 1.0000x reference)
//
#include <hip/hip_runtime.h>
#include <hip/hip_bf16.h>

// FlashAttention fwd, B=2 L=2048 H=16 D=64, fp32 in/out, layout [B,L,H,D].
// bf16 MFMA 16x16x32, fp32 accum. Swapped QK^T (mfma(K,Q) -> S^T) so softmax
// is lane-local. K LDS XOR-swizzled; V LDS 8-interleaved for b128 B-frags.

#define L_    2048
#define H_    16
#define D_    64
#define HD    1024      // H_*D_ row stride (floats)
#define QBLK  128
#define KVBLK 64
#define NQT   (L_ / QBLK)   // 16

typedef short s16x8 __attribute__((ext_vector_type(8)));
typedef short s16x4 __attribute__((ext_vector_type(4)));
typedef float f32x4 __attribute__((ext_vector_type(4)));

static __device__ __forceinline__ short f2bf(float f) {
    __hip_bfloat16 h = __float2bfloat16(f);
    return *reinterpret_cast<short*>(&h);
}

__global__ __launch_bounds__(512, 2)
void fattn_kernel(const float* __restrict__ Qg, const float* __restrict__ Kg,
                  const float* __restrict__ Vg, float* __restrict__ Og)
{
    __shared__ __align__(16) short lds_k[KVBLK * D_];      // swizzled row-major [kv][d]
    __shared__ __align__(16) short lds_v[KVBLK * D_];      // 8-interleaved [kv>>3][d][kv&7]
    __shared__ __align__(16) short lds_p[8][16 * KVBLK];   // per-wave P[q][kv], swizzled

    const int tid  = threadIdx.x;
    const int wave = tid >> 6;
    const int lane = tid & 63;
    const int q16  = lane & 15;   // q-row within wave tile / frag col
    const int g    = lane >> 4;   // 4-lane-group

    // XCD-bijective swizzle: 512 blocks = 8 XCDs x 64 contiguous
    const int bid  = blockIdx.x;
    const int virt = (bid & 7) * 64 + (bid >> 3);
    const int bh   = virt / NQT;        // 0..31
    const int qt   = virt % NQT;        // 0..15
    const int b    = bh >> 4;           // /H_
    const int h    = bh & 15;

    const size_t base = (size_t)b * L_ * HD + (size_t)h * D_;
    const float* Qp = Qg + base;
    const float* Kp = Kg + base;
    const float* Vp = Vg + base;
    float*       Op = Og + base;

    // ---- Q fragment (lane: row q16, k = 32c + 8g + j), pre-scaled by 1/sqrt(D)
    s16x8 qf[2];
    {
        const float* qrow = Qp + (size_t)(qt * QBLK + wave * 16 + q16) * HD;
        #pragma unroll
        for (int c = 0; c < 2; ++c) {
            const float4 f0 = *reinterpret_cast<const float4*>(qrow + 32 * c + 8 * g);
            const float4 f1 = *reinterpret_cast<const float4*>(qrow + 32 * c + 8 * g + 4);
            s16x8 t;
            t[0] = f2bf(f0.x * 0.125f); t[1] = f2bf(f0.y * 0.125f);
            t[2] = f2bf(f0.z * 0.125f); t[3] = f2bf(f0.w * 0.125f);
            t[4] = f2bf(f1.x * 0.125f); t[5] = f2bf(f1.y * 0.125f);
            t[6] = f2bf(f1.z * 0.125f); t[7] = f2bf(f1.w * 0.125f);
            qf[c] = t;
        }
    }

    f32x4 o[4];
    #pragma unroll
    for (int i = 0; i < 4; ++i) o[i] = (f32x4){0.f, 0.f, 0.f, 0.f};
    float m_run = -INFINITY, l_run = 0.f;

    for (int kv0 = 0; kv0 < L_; kv0 += KVBLK) {
        __syncthreads();   // previous tile's K/V reads complete
        if (tid < 256) {
            // ---- stage V: 8-interleaved layout, elem = (kv>>3)*512 + d*8 + (kv&7)
            const int kvq = tid >> 4;            // kv quad 0..15
            const int d0  = (tid & 15) << 2;     // 0,4,...,60
            const float* vb0 = Vp + (size_t)(kv0 + kvq * 4) * HD + d0;
            const float4 r0 = *reinterpret_cast<const float4*>(vb0);
            const float4 r1 = *reinterpret_cast<const float4*>(vb0 + HD);
            const float4 r2 = *reinterpret_cast<const float4*>(vb0 + 2 * HD);
            const float4 r3 = *reinterpret_cast<const float4*>(vb0 + 3 * HD);
            const float c0[4] = {r0.x, r0.y, r0.z, r0.w};
            const float c1[4] = {r1.x, r1.y, r1.z, r1.w};
            const float c2[4] = {r2.x, r2.y, r2.z, r2.w};
            const float c3[4] = {r3.x, r3.y, r3.z, r3.w};
            const int ebase = (kvq >> 1) * 512 + (kvq & 1) * 4;
            #pragma unroll
            for (int dd = 0; dd < 4; ++dd) {
                s16x4 w;
                w[0] = f2bf(c0[dd]); w[1] = f2bf(c1[dd]);
                w[2] = f2bf(c2[dd]); w[3] = f2bf(c3[dd]);
                *reinterpret_cast<s16x4*>(&lds_v[ebase + (d0 + dd) * 8]) = w;
            }
        } else {
            // ---- stage K: row-major, elem = (row*64 + d) ^ ((row&7)<<3)
            const int t2  = tid - 256;
            const int row = t2 >> 2;
            const int d0  = (t2 & 3) << 4;
            const float* kr = Kp + (size_t)(kv0 + row) * HD + d0;
            const float4 f0 = *reinterpret_cast<const float4*>(kr);
            const float4 f1 = *reinterpret_cast<const float4*>(kr + 4);
            const float4 f2 = *reinterpret_cast<const float4*>(kr + 8);
            const float4 f3 = *reinterpret_cast<const float4*>(kr + 12);
            s16x8 w0, w1;
            w0[0] = f2bf(f0.x); w0[1] = f2bf(f0.y); w0[2] = f2bf(f0.z); w0[3] = f2bf(f0.w);
            w0[4] = f2bf(f1.x); w0[5] = f2bf(f1.y); w0[6] = f2bf(f1.z); w0[7] = f2bf(f1.w);
            w1[0] = f2bf(f2.x); w1[1] = f2bf(f2.y); w1[2] = f2bf(f2.z); w1[3] = f2bf(f2.w);
            w1[4] = f2bf(f3.x); w1[5] = f2bf(f3.y); w1[6] = f2bf(f3.z); w1[7] = f2bf(f3.w);
            const int swz = (row & 7) << 3;
            const int e   = row * 64 + d0;
            *reinterpret_cast<s16x8*>(&lds_k[(e    ) ^ swz]) = w0;
            *reinterpret_cast<s16x8*>(&lds_k[(e + 8) ^ swz]) = w1;
        }
        __syncthreads();

        // ---- S^T = K_tile x Q : lane holds S[q=q16][kv = 16*mt + 4*g + r]
        f32x4 st[4];
        #pragma unroll
        for (int mt = 0; mt < 4; ++mt) {
            st[mt] = (f32x4){0.f, 0.f, 0.f, 0.f};
            #pragma unroll
            for (int c = 0; c < 2; ++c) {
                const int row = mt * 16 + q16;
                const int e   = (row * 64 + 32 * c + 8 * g) ^ ((row & 7) << 3);
                const s16x8 kf = *reinterpret_cast<const s16x8*>(&lds_k[e]);
                st[mt] = __builtin_amdgcn_mfma_f32_16x16x32_bf16(kf, qf[c], st[mt], 0, 0, 0);
            }
        }

        // ---- online softmax (row is lane-local; 4 redundant copies across g)
        float tmax = -INFINITY;
        #pragma unroll
        for (int mt = 0; mt < 4; ++mt)
            #pragma unroll
            for (int r = 0; r < 4; ++r) tmax = fmaxf(tmax, st[mt][r]);
        tmax = fmaxf(tmax, __shfl_xor(tmax, 16));
        tmax = fmaxf(tmax, __shfl_xor(tmax, 32));
        const float m_new = fmaxf(m_run, tmax);
        const float alpha = __expf(m_run - m_new);   // first tile: exp(-inf)=0
        float p[16];
        float psum = 0.f;
        #pragma unroll
        for (int mt = 0; mt < 4; ++mt)
            #pragma unroll
            for (int r = 0; r < 4; ++r) {
                const float e = __expf(st[mt][r] - m_new);
                p[mt * 4 + r] = e;
                psum += e;
            }
        psum += __shfl_xor(psum, 16);
        psum += __shfl_xor(psum, 32);
        l_run = l_run * alpha + psum;
        m_run = m_new;

        // rescale O: alpha for O-row (4g+r) lives on lane (4g+r)
        float alpha_o[4];
        #pragma unroll
        for (int r = 0; r < 4; ++r) alpha_o[r] = __shfl(alpha, 4 * g + r);
        #pragma unroll
        for (int n = 0; n < 4; ++n)
            #pragma unroll
            for (int r = 0; r < 4; ++r) o[n][r] *= alpha_o[r];

        // ---- P^T(regs) -> lds_p[wave] as P[q][kv], swizzled; then A-frag reads
        {
            short* pl = lds_p[wave];
            const int pswz = (q16 & 7) << 3;
            #pragma unroll
            for (int mt = 0; mt < 4; ++mt)
                #pragma unroll
                for (int r = 0; r < 4; ++r) {
                    const int kv = mt * 16 + 4 * g + r;
                    pl[(q16 * 64 + kv) ^ pswz] = f2bf(p[mt * 4 + r]);
                }
        }
        asm volatile("s_waitcnt lgkmcnt(0)" ::: "memory");  // wave-local RAW fence
        s16x8 pa[2];
        #pragma unroll
        for (int c = 0; c < 2; ++c) {
            const int e = (q16 * 64 + 32 * c + 8 * g) ^ ((q16 & 7) << 3);
            pa[c] = *reinterpret_cast<const s16x8*>(&lds_p[wave][e]);
        }

        // ---- O += P x V  (V B-frag: one b128 per (c,n) from 8-interleaved LDS)
        #pragma unroll
        for (int c = 0; c < 2; ++c) {
            #pragma unroll
            for (int n = 0; n < 4; ++n) {
                const int d = n * 16 + q16;
                const s16x8 vb = *reinterpret_cast<const s16x8*>(
                    &lds_v[(4 * c + g) * 512 + d * 8]);
                o[n] = __builtin_amdgcn_mfma_f32_16x16x32_bf16(pa[c], vb, o[n], 0, 0, 0);
            }
        }
    }

    // ---- epilogue: normalize and store (O row for (4g+r) uses lane (4g+r)'s l)
    float linv[4];
    #pragma unroll
    for (int r = 0; r < 4; ++r) linv[r] = 1.f / __shfl(l_run, 4 * g + r);
    float* orow_base = Op + (size_t)(qt * QBLK + wave * 16) * HD;
    #pragma unroll
    for (int r = 0; r < 4; ++r) {
        float* orow = orow_base + (size_t)(4 * g + r) * HD;
        #pragma unroll
        for (int n = 0; n < 4; ++n)
            orow[n * 16 + q16] = o[n][r] * linv[r];
    }
}

extern "C" void kernel_launch(void* const* d_in, const int* in_sizes, int n_in,
                              void* d_out, int out_size, void* d_ws, size_t ws_size,
                              hipStream_t stream) {
    const float* q = (const float*)d_in[0];
    const float* k = (const float*)d_in[1];
    const float* v = (const float*)d_in[2];
    float* out = (float*)d_out;
    // grid: 2*16 (b,h) x 16 q-tiles = 512 blocks, 512 threads
    fattn_kernel<<<dim3(512), dim3(512), 0, stream>>>(q, k, v, out);
}

// Round 11
// 153.233 us; speedup vs baseline: 1.1037x; 1.1037x over previous
//
#include <hip/hip_runtime.h>
#include <hip/hip_bf16.h>

// FlashAttention fwd, B=2 L=2048 H=16 D=64, fp32 in/out, layout [B,L,H,D].
// bf16 MFMA 16x16x32, fp32 accum. Swapped QK^T (mfma(K,Q) -> S^T), lane-local
// softmax. R6: conflict-free K/V staging (1 b128/thread), K/V LDS
// double-buffered, T14 issue-early/write-late, 1 barrier per KV tile.

#define L_    2048
#define H_    16
#define D_    64
#define HD    1024      // H_*D_ row stride (floats)
#define QBLK  128
#define KVBLK 64
#define NQT   (L_ / QBLK)   // 16
#define NT    (L_ / KVBLK)  // 32

typedef short s16x8 __attribute__((ext_vector_type(8)));
typedef float f32x4 __attribute__((ext_vector_type(4)));

static __device__ __forceinline__ short f2bf(float f) {
    __hip_bfloat16 h = __float2bfloat16(f);
    return *reinterpret_cast<short*>(&h);
}

__global__ __launch_bounds__(512, 2)
void fattn_kernel(const float* __restrict__ Qg, const float* __restrict__ Kg,
                  const float* __restrict__ Vg, float* __restrict__ Og)
{
    // K: swizzled row-major [kv][d], elem = (kv*64+d) ^ ((kv&7)<<3)
    // V: 8-interleaved [kv>>3][d][kv&7], elem = ks*512 + d*8 + (kv&7)
    __shared__ __align__(16) short lds_k[2][KVBLK * D_];
    __shared__ __align__(16) short lds_v[2][KVBLK * D_];
    __shared__ __align__(16) short lds_p[8][16 * KVBLK];   // per-wave P[q][kv], swizzled

    const int tid  = threadIdx.x;
    const int wave = tid >> 6;
    const int lane = tid & 63;
    const int q16  = lane & 15;   // q-row within wave tile / frag col
    const int g    = lane >> 4;   // 4-lane-group

    // XCD-bijective swizzle: 512 blocks = 8 XCDs x 64 contiguous
    const int bid  = blockIdx.x;
    const int virt = (bid & 7) * 64 + (bid >> 3);
    const int bh   = virt / NQT;        // 0..31
    const int qt   = virt % NQT;        // 0..15
    const int b    = bh >> 4;           // /H_
    const int h    = bh & 15;

    const size_t base = (size_t)b * L_ * HD + (size_t)h * D_;
    const float* Qp = Qg + base;
    const float* Kp = Kg + base;
    const float* Vp = Vg + base;
    float*       Op = Og + base;

    // ---- staging roles (all 512 threads stage both one V chunk and one K chunk)
    const int vks  = tid >> 6;            // 0..7 : kv-octet
    const int vd   = tid & 63;            // 0..63: d column (coalesced across wave)
    const int krow = tid >> 3;            // 0..63
    const int kd0  = (tid & 7) << 3;      // 0,8,...,56
    const float* vcol  = Vp + vd;
    const float* krowp = Kp + (size_t)krow * HD + kd0;

    float  vreg[8];
    float4 kreg[2];

    // ---- Q fragment (lane: row q16, k = 32c + 8g + j), pre-scaled by 1/sqrt(D)
    s16x8 qf[2];
    {
        const float* qrow = Qp + (size_t)(qt * QBLK + wave * 16 + q16) * HD;
        #pragma unroll
        for (int c = 0; c < 2; ++c) {
            const float4 f0 = *reinterpret_cast<const float4*>(qrow + 32 * c + 8 * g);
            const float4 f1 = *reinterpret_cast<const float4*>(qrow + 32 * c + 8 * g + 4);
            s16x8 t;
            t[0] = f2bf(f0.x * 0.125f); t[1] = f2bf(f0.y * 0.125f);
            t[2] = f2bf(f0.z * 0.125f); t[3] = f2bf(f0.w * 0.125f);
            t[4] = f2bf(f1.x * 0.125f); t[5] = f2bf(f1.y * 0.125f);
            t[6] = f2bf(f1.z * 0.125f); t[7] = f2bf(f1.w * 0.125f);
            qf[c] = t;
        }
    }

    f32x4 o[4];
    #pragma unroll
    for (int i = 0; i < 4; ++i) o[i] = (f32x4){0.f, 0.f, 0.f, 0.f};
    float m_run = -INFINITY, l_run = 0.f;

    // ---- prologue: stage tile 0 into buf 0
    {
        #pragma unroll
        for (int j = 0; j < 8; ++j)
            vreg[j] = vcol[(size_t)(8 * vks + j) * HD];
        kreg[0] = *reinterpret_cast<const float4*>(krowp);
        kreg[1] = *reinterpret_cast<const float4*>(krowp + 4);
        s16x8 wv, wk;
        #pragma unroll
        for (int j = 0; j < 8; ++j) wv[j] = f2bf(vreg[j]);
        wk[0] = f2bf(kreg[0].x); wk[1] = f2bf(kreg[0].y);
        wk[2] = f2bf(kreg[0].z); wk[3] = f2bf(kreg[0].w);
        wk[4] = f2bf(kreg[1].x); wk[5] = f2bf(kreg[1].y);
        wk[6] = f2bf(kreg[1].z); wk[7] = f2bf(kreg[1].w);
        *reinterpret_cast<s16x8*>(&lds_v[0][vks * 512 + vd * 8]) = wv;
        *reinterpret_cast<s16x8*>(&lds_k[0][(krow * 64 + kd0) ^ ((krow & 7) << 3)]) = wk;
    }

    for (int t = 0; t < NT; ++t) {
        const int cur = t & 1;
        __syncthreads();   // buf[cur] staged; prev compute's reads of buf[cur^1] done

        // ---- T14 issue-early: global loads for tile t+1 (latency hides under compute)
        if (t + 1 < NT) {
            const int kv0n = (t + 1) * KVBLK;
            #pragma unroll
            for (int j = 0; j < 8; ++j)
                vreg[j] = vcol[(size_t)(kv0n + 8 * vks + j) * HD];
            const float* kp = krowp + (size_t)kv0n * HD;
            kreg[0] = *reinterpret_cast<const float4*>(kp);
            kreg[1] = *reinterpret_cast<const float4*>(kp + 4);
        }
        __builtin_amdgcn_sched_barrier(0);   // keep loads issued before compute

        // ---- S^T = K_tile x Q : lane holds S[q=q16][kv = 16*mt + 4*g + r]
        f32x4 st[4];
        #pragma unroll
        for (int mt = 0; mt < 4; ++mt) {
            st[mt] = (f32x4){0.f, 0.f, 0.f, 0.f};
            #pragma unroll
            for (int c = 0; c < 2; ++c) {
                const int row = mt * 16 + q16;
                const int e   = (row * 64 + 32 * c + 8 * g) ^ ((row & 7) << 3);
                const s16x8 kf = *reinterpret_cast<const s16x8*>(&lds_k[cur][e]);
                st[mt] = __builtin_amdgcn_mfma_f32_16x16x32_bf16(kf, qf[c], st[mt], 0, 0, 0);
            }
        }

        // ---- online softmax (row lane-local; 4 redundant copies across g)
        float tmax = -INFINITY;
        #pragma unroll
        for (int mt = 0; mt < 4; ++mt)
            #pragma unroll
            for (int r = 0; r < 4; ++r) tmax = fmaxf(tmax, st[mt][r]);
        tmax = fmaxf(tmax, __shfl_xor(tmax, 16));
        tmax = fmaxf(tmax, __shfl_xor(tmax, 32));
        const float m_new = fmaxf(m_run, tmax);
        const float alpha = __expf(m_run - m_new);   // first tile: exp(-inf)=0
        float p[16];
        float psum = 0.f;
        #pragma unroll
        for (int mt = 0; mt < 4; ++mt)
            #pragma unroll
            for (int r = 0; r < 4; ++r) {
                const float e = __expf(st[mt][r] - m_new);
                p[mt * 4 + r] = e;
                psum += e;
            }
        psum += __shfl_xor(psum, 16);
        psum += __shfl_xor(psum, 32);
        l_run = l_run * alpha + psum;
        m_run = m_new;

        // rescale O: alpha for O-row (4g+r) lives on lane (4g+r)
        float alpha_o[4];
        #pragma unroll
        for (int r = 0; r < 4; ++r) alpha_o[r] = __shfl(alpha, 4 * g + r);
        #pragma unroll
        for (int n = 0; n < 4; ++n)
            #pragma unroll
            for (int r = 0; r < 4; ++r) o[n][r] *= alpha_o[r];

        // ---- P^T(regs) -> lds_p[wave] as P[q][kv], swizzled; then A-frag reads
        {
            short* pl = lds_p[wave];
            const int pswz = (q16 & 7) << 3;
            #pragma unroll
            for (int mt = 0; mt < 4; ++mt)
                #pragma unroll
                for (int r = 0; r < 4; ++r) {
                    const int kv = mt * 16 + 4 * g + r;
                    pl[(q16 * 64 + kv) ^ pswz] = f2bf(p[mt * 4 + r]);
                }
        }
        asm volatile("s_waitcnt lgkmcnt(0)" ::: "memory");  // wave-local RAW fence
        s16x8 pa[2];
        #pragma unroll
        for (int c = 0; c < 2; ++c) {
            const int e = (q16 * 64 + 32 * c + 8 * g) ^ ((q16 & 7) << 3);
            pa[c] = *reinterpret_cast<const s16x8*>(&lds_p[wave][e]);
        }

        // ---- O += P x V  (V B-frag: one b128 per (c,n), conflict-free)
        #pragma unroll
        for (int c = 0; c < 2; ++c) {
            #pragma unroll
            for (int n = 0; n < 4; ++n) {
                const int d = n * 16 + q16;
                const s16x8 vb = *reinterpret_cast<const s16x8*>(
                    &lds_v[cur][(4 * c + g) * 512 + d * 8]);
                o[n] = __builtin_amdgcn_mfma_f32_16x16x32_bf16(pa[c], vb, o[n], 0, 0, 0);
            }
        }

        __builtin_amdgcn_sched_barrier(0);   // keep cvt+write after compute
        // ---- T14 write-late: convert and stage tile t+1 into the other buffer
        if (t + 1 < NT) {
            s16x8 wv, wk;
            #pragma unroll
            for (int j = 0; j < 8; ++j) wv[j] = f2bf(vreg[j]);
            wk[0] = f2bf(kreg[0].x); wk[1] = f2bf(kreg[0].y);
            wk[2] = f2bf(kreg[0].z); wk[3] = f2bf(kreg[0].w);
            wk[4] = f2bf(kreg[1].x); wk[5] = f2bf(kreg[1].y);
            wk[6] = f2bf(kreg[1].z); wk[7] = f2bf(kreg[1].w);
            *reinterpret_cast<s16x8*>(&lds_v[cur ^ 1][vks * 512 + vd * 8]) = wv;
            *reinterpret_cast<s16x8*>(
                &lds_k[cur ^ 1][(krow * 64 + kd0) ^ ((krow & 7) << 3)]) = wk;
        }
    }

    // ---- epilogue: normalize and store (O row (4g+r) uses lane (4g+r)'s l)
    float linv[4];
    #pragma unroll
    for (int r = 0; r < 4; ++r) linv[r] = 1.f / __shfl(l_run, 4 * g + r);
    float* orow_base = Op + (size_t)(qt * QBLK + wave * 16) * HD;
    #pragma unroll
    for (int r = 0; r < 4; ++r) {
        float* orow = orow_base + (size_t)(4 * g + r) * HD;
        #pragma unroll
        for (int n = 0; n < 4; ++n)
            orow[n * 16 + q16] = o[n][r] * linv[r];
    }
}

extern "C" void kernel_launch(void* const* d_in, const int* in_sizes, int n_in,
                              void* d_out, int out_size, void* d_ws, size_t ws_size,
                              hipStream_t stream) {
    const float* q = (const float*)d_in[0];
    const float* k = (const float*)d_in[1];
    const float* v = (const float*)d_in[2];
    float* out = (float*)d_out;
    // grid: 2*16 (b,h) x 16 q-tiles = 512 blocks, 512 threads
    fattn_kernel<<<dim3(512), dim3(512), 0, stream>>>(q, k, v, out);
}